// Round 1
// baseline (532.248 us; speedup 1.0000x reference)
//
#include <hip/hip_runtime.h>
#include <hip/hip_bf16.h>

typedef __bf16 bf16x8 __attribute__((ext_vector_type(8)));
typedef float floatx4 __attribute__((ext_vector_type(4)));
typedef unsigned short ushortx8 __attribute__((ext_vector_type(8)));

#define FP8_MAX 448.0f
#define QEPS 1e-8f

// async 16B global -> LDS (dest must be wave-uniform base + lane*16)
#define GLLDS16(gptr, lptr)                                                          \
  __builtin_amdgcn_global_load_lds((const __attribute__((address_space(1))) void*)(gptr), \
                                   (__attribute__((address_space(3))) void*)(lptr), 16, 0, 0)

// ---------------------------------------------------------------------------
// fp8-e4m3 groupwise pseudo-quantize (group=32 along last dim) -> bf16 dequant
// ---------------------------------------------------------------------------
__global__ __launch_bounds__(256) void quant_dq_kernel(
    const float* __restrict__ src, __hip_bfloat16* __restrict__ dst, long long n)
{
    long long t = (long long)blockIdx.x * blockDim.x + threadIdx.x;
    long long base = t * 8;
    if (base >= n) return;

    const float4 v0 = *(const float4*)(src + base);
    const float4 v1 = *(const float4*)(src + base + 4);

    float am = fmaxf(
        fmaxf(fmaxf(fabsf(v0.x), fabsf(v0.y)), fmaxf(fabsf(v0.z), fabsf(v0.w))),
        fmaxf(fmaxf(fabsf(v1.x), fabsf(v1.y)), fmaxf(fabsf(v1.z), fabsf(v1.w))));
    am = fmaxf(am, __shfl_xor(am, 1));
    am = fmaxf(am, __shfl_xor(am, 2));
    const float scale = fmaxf(am, QEPS) / FP8_MAX;

    int p0 = __builtin_amdgcn_cvt_pk_fp8_f32(v0.x / scale, v0.y / scale, 0, false);
    int p1 = __builtin_amdgcn_cvt_pk_fp8_f32(v0.z / scale, v0.w / scale, 0, false);
    int p2 = __builtin_amdgcn_cvt_pk_fp8_f32(v1.x / scale, v1.y / scale, 0, false);
    int p3 = __builtin_amdgcn_cvt_pk_fp8_f32(v1.z / scale, v1.w / scale, 0, false);

    float r0 = __builtin_amdgcn_cvt_f32_fp8(p0, 0) * scale;
    float r1 = __builtin_amdgcn_cvt_f32_fp8(p0, 1) * scale;
    float r2 = __builtin_amdgcn_cvt_f32_fp8(p1, 0) * scale;
    float r3 = __builtin_amdgcn_cvt_f32_fp8(p1, 1) * scale;
    float r4 = __builtin_amdgcn_cvt_f32_fp8(p2, 0) * scale;
    float r5 = __builtin_amdgcn_cvt_f32_fp8(p2, 1) * scale;
    float r6 = __builtin_amdgcn_cvt_f32_fp8(p3, 0) * scale;
    float r7 = __builtin_amdgcn_cvt_f32_fp8(p3, 1) * scale;

    alignas(16) __hip_bfloat16 hb[8] = {
        __float2bfloat16(r0), __float2bfloat16(r1),
        __float2bfloat16(r2), __float2bfloat16(r3),
        __float2bfloat16(r4), __float2bfloat16(r5),
        __float2bfloat16(r6), __float2bfloat16(r7)};
    *(ushortx8*)(dst + base) = *(const ushortx8*)hb;
}

// ---------------------------------------------------------------------------
// bf16 NT GEMM + bias: 256x256 tile, BK=64, 512 thr (8 waves 2Mx4N),
// 8-phase counted-vmcnt schedule. See analysis: T2 chunk-XOR swizzle,
// T3/T4 counted vmcnt(6) at phases 4+8 (never 0 mid-loop), T5 setprio,
// T1 XCD block swizzle. LDS slots re-staged >=1 phase after last read.
// Assumes M%256==0, N%256==0, K%128==0 (holds: 8192/4096/4096).
// ---------------------------------------------------------------------------

#define BAR() __builtin_amdgcn_s_barrier()
#define LGKM0()                                              \
  do {                                                       \
    asm volatile("s_waitcnt lgkmcnt(0)" ::: "memory");       \
    __builtin_amdgcn_sched_barrier(0);                       \
  } while (0)
#define VMCNT(n) asm volatile("s_waitcnt vmcnt(" #n ")" ::: "memory")

#define STAGE_A(a_, t_, b_)                                                   \
  do {                                                                        \
    const __hip_bfloat16* g_ = gAs + (long)(a_) * 128 * K + (long)(t_) * 64;  \
    __hip_bfloat16* l_ = &sA[(b_)][(a_) * 8192 + tid * 8];                    \
    GLLDS16(g_, l_);                                                          \
    GLLDS16(g_ + 64 * (long)K, l_ + 4096);                                    \
  } while (0)

#define STAGE_B(a_, t_, b_)                                                   \
  do {                                                                        \
    const __hip_bfloat16* g_ = gBs + (long)(a_) * 128 * K + (long)(t_) * 64;  \
    __hip_bfloat16* l_ = &sB[(b_)][(a_) * 8192 + tid * 8];                    \
    GLLDS16(g_, l_);                                                          \
    GLLDS16(g_ + 64 * (long)K, l_ + 4096);                                    \
  } while (0)

#define LOAD_A(buf, mh)                                                       \
  do {                                                                        \
    _Pragma("unroll") for (int mm = 0; mm < 4; ++mm)                          \
    _Pragma("unroll") for (int ks = 0; ks < 2; ++ks)                          \
        af[mm][ks] = *(const bf16x8*)((buf) + ((mh)*4 + mm) * 1024 + aoff[ks]); \
  } while (0)

#define LOAD_B(buf, nh)                                                       \
  do {                                                                        \
    _Pragma("unroll") for (int nn = 0; nn < 2; ++nn)                          \
    _Pragma("unroll") for (int ks = 0; ks < 2; ++ks)                          \
        bfr[nh][nn][ks] = *(const bf16x8*)((buf) + (nh)*2048 + nn * 1024 + boff[ks]); \
  } while (0)

#define QUAD(mh, nh)                                                          \
  do {                                                                        \
    __builtin_amdgcn_s_setprio(1);                                            \
    _Pragma("unroll") for (int ks = 0; ks < 2; ++ks)                          \
    _Pragma("unroll") for (int mm = 0; mm < 4; ++mm)                          \
    _Pragma("unroll") for (int nn = 0; nn < 2; ++nn)                          \
        acc[(mh)*4 + mm][(nh)*2 + nn] = __builtin_amdgcn_mfma_f32_16x16x32_bf16( \
            af[mm][ks], bfr[nh][nn][ks], acc[(mh)*4 + mm][(nh)*2 + nn], 0, 0, 0); \
    __builtin_amdgcn_s_setprio(0);                                            \
  } while (0)

__global__ __launch_bounds__(512, 2) void gemm_bias_kernel(
    const __hip_bfloat16* __restrict__ A,   // [M][K]
    const __hip_bfloat16* __restrict__ B,   // [N][K]
    const float* __restrict__ bias,         // [N]
    float* __restrict__ C,                  // [M][N]
    int M, int N, int K)
{
    __shared__ __attribute__((aligned(16))) __hip_bfloat16 sA[2][256 * 64];
    __shared__ __attribute__((aligned(16))) __hip_bfloat16 sB[2][256 * 64];

    const int tid  = threadIdx.x;
    const int lane = tid & 63;
    const int wave = tid >> 6;
    const int wm   = wave >> 2;   // 0..1 : 128-row half
    const int wn   = wave & 3;    // 0..3 : 64-col slice

    // T1: XCD-aware bijective block swizzle (nwg % 8 == 0 for these shapes)
    const int nwg = gridDim.x;
    const int wg  = blockIdx.x;
    int swz = wg;
    if ((nwg & 7) == 0) swz = (wg & 7) * (nwg >> 3) + (wg >> 3);
    const int NXB = N >> 8;
    const long bm = (long)(swz / NXB) * 256;
    const long bn = (long)(swz % NXB) * 256;

    // staging: 512 thr * 16B = 64 rows (128B each) per GLLDS16 call
    const int srow   = tid >> 3;                   // 0..63
    const int schunk = (tid & 7) ^ (srow & 7);     // pre-swizzled global chunk
    const __hip_bfloat16* gAs = A + (bm + srow) * (long)K + schunk * 8;
    const __hip_bfloat16* gBs = B + (bn + srow) * (long)K + schunk * 8;

    const int fr = lane & 15;
    const int fq = lane >> 4;
    const int f7 = fr & 7;
    int aoff[2], boff[2];
#pragma unroll
    for (int ks = 0; ks < 2; ++ks) {
        const int ch = ((ks * 4 + fq) ^ f7) * 8;
        aoff[ks] = (wm * 128 + fr) * 64 + ch;
        boff[ks] = (wn * 64 + fr) * 64 + ch;
    }

    floatx4 acc[8][4];
#pragma unroll
    for (int i = 0; i < 8; ++i)
#pragma unroll
        for (int j = 0; j < 4; ++j)
            acc[i][j] = (floatx4){0.f, 0.f, 0.f, 0.f};

    bf16x8 af[4][2];        // current m-half A frags
    bf16x8 bfr[2][2][2];    // [nh][nn][ks] B frags, full K-tile

    const int NT = K >> 6;
    const int NI = NT >> 1;

    // prologue: tile0 fully -> buf0; tile1 B0,B1,A0 -> buf1 (A1 comes in ph1)
    STAGE_A(0, 0, 0); STAGE_A(1, 0, 0);
    STAGE_B(0, 0, 0); STAGE_B(1, 0, 0);
    if (NT > 1) { STAGE_B(0, 1, 1); STAGE_B(1, 1, 1); STAGE_A(0, 1, 1); }
    VMCNT(6);
    BAR();

#pragma unroll 1
    for (int i = 0; i < NI; ++i) {
        const bool more = (i + 1 < NI);
        const int t1 = 2 * i + 1, t2 = 2 * i + 2, t3 = 2 * i + 3;

        // ===== tile 2i from buf0 =====
        LOAD_A(sA[0], 0); LOAD_B(sB[0], 0);           // ph1: 12 reads
        STAGE_A(1, t1, 1);
        BAR(); LGKM0();
        QUAD(0, 0);
        BAR();

        LOAD_B(sB[0], 1);                             // ph2: 4 reads
        BAR(); LGKM0();
        QUAD(0, 1);
        BAR();

        LOAD_A(sA[0], 1);                             // ph3: 8 reads
        if (more) STAGE_B(0, t2, 0);
        BAR(); LGKM0();
        QUAD(1, 0);
        BAR();

        if (more) { STAGE_B(1, t2, 0); STAGE_A(0, t2, 0); }   // ph4
        BAR();
        QUAD(1, 1);
        if (more) { VMCNT(6); } else { VMCNT(0); }
        BAR();

        // ===== tile 2i+1 from buf1 =====
        LOAD_A(sA[1], 0); LOAD_B(sB[1], 0);           // ph5
        if (more) STAGE_A(1, t2, 0);
        BAR(); LGKM0();
        QUAD(0, 0);
        BAR();

        LOAD_B(sB[1], 1);                             // ph6
        BAR(); LGKM0();
        QUAD(0, 1);
        BAR();

        LOAD_A(sA[1], 1);                             // ph7
        if (more) STAGE_B(0, t3, 1);
        BAR(); LGKM0();
        QUAD(1, 0);
        BAR();

        if (more) { STAGE_B(1, t3, 1); STAGE_A(0, t3, 1); }   // ph8
        BAR();
        QUAD(1, 1);
        if (more) { VMCNT(6); }
        BAR();
    }

    // epilogue: C/D layout col=lane&15, row=(lane>>4)*4+reg  [m89/m91]
    const int rq = (lane >> 4) * 4;
#pragma unroll
    for (int j = 0; j < 4; ++j) {
        const long gc = bn + wn * 64 + j * 16 + fr;
        const float bj = bias[gc];
#pragma unroll
        for (int mf = 0; mf < 8; ++mf) {
            const long gr = bm + wm * 128 + mf * 16 + rq;
            float* cp = C + gr * (long)N + gc;
#pragma unroll
            for (int r = 0; r < 4; ++r)
                cp[(long)r * N] = acc[mf][j][r] + bj;
        }
    }
}

extern "C" void kernel_launch(void* const* d_in, const int* in_sizes, int n_in,
                              void* d_out, int out_size, void* d_ws, size_t ws_size,
                              hipStream_t stream) {
    const float* x    = (const float*)d_in[0];   // [B,S,K] fp32
    const float* W    = (const float*)d_in[1];   // [N,K]   fp32
    const float* bias = (const float*)d_in[2];   // [N]     fp32
    float* out = (float*)d_out;

    const long long nx = in_sizes[0];
    const long long nw = in_sizes[1];
    const int N = in_sizes[2];
    const int K = (int)(nw / N);
    const int M = (int)(nx / K);

    __hip_bfloat16* xq = (__hip_bfloat16*)d_ws;
    __hip_bfloat16* wq = xq + nx;

    {
        long long tx = nx / 8;
        int blocks = (int)((tx + 255) / 256);
        quant_dq_kernel<<<blocks, 256, 0, stream>>>(x, xq, nx);
    }
    {
        long long tw = nw / 8;
        int blocks = (int)((tw + 255) / 256);
        quant_dq_kernel<<<blocks, 256, 0, stream>>>(W, wq, nw);
    }

    dim3 grid((N / 256) * (M / 256));
    gemm_bias_kernel<<<grid, 512, 0, stream>>>(xq, wq, bias, out, M, N, K);
}

// Round 2
// 530.524 us; speedup vs baseline: 1.0032x; 1.0032x over previous
//
#include <hip/hip_runtime.h>
#include <hip/hip_bf16.h>

typedef __bf16 bf16x8 __attribute__((ext_vector_type(8)));
typedef float floatx4 __attribute__((ext_vector_type(4)));
typedef unsigned short ushortx8 __attribute__((ext_vector_type(8)));

#define FP8_MAX 448.0f
#define QEPS 1e-8f

// async 16B global -> LDS (dest must be wave-uniform base + lane*16)
#define GLLDS16(gptr, lptr)                                                          \
  __builtin_amdgcn_global_load_lds((const __attribute__((address_space(1))) void*)(gptr), \
                                   (__attribute__((address_space(3))) void*)(lptr), 16, 0, 0)

// ---------------------------------------------------------------------------
// fp8-e4m3 groupwise pseudo-quantize (group=32 along last dim) -> bf16 dequant
// ---------------------------------------------------------------------------
__global__ __launch_bounds__(256) void quant_dq_kernel(
    const float* __restrict__ src, __hip_bfloat16* __restrict__ dst, long long n)
{
    long long t = (long long)blockIdx.x * blockDim.x + threadIdx.x;
    long long base = t * 8;
    if (base >= n) return;

    const float4 v0 = *(const float4*)(src + base);
    const float4 v1 = *(const float4*)(src + base + 4);

    float am = fmaxf(
        fmaxf(fmaxf(fabsf(v0.x), fabsf(v0.y)), fmaxf(fabsf(v0.z), fabsf(v0.w))),
        fmaxf(fmaxf(fabsf(v1.x), fabsf(v1.y)), fmaxf(fabsf(v1.z), fabsf(v1.w))));
    am = fmaxf(am, __shfl_xor(am, 1));
    am = fmaxf(am, __shfl_xor(am, 2));
    const float scale = fmaxf(am, QEPS) / FP8_MAX;

    int p0 = __builtin_amdgcn_cvt_pk_fp8_f32(v0.x / scale, v0.y / scale, 0, false);
    int p1 = __builtin_amdgcn_cvt_pk_fp8_f32(v0.z / scale, v0.w / scale, 0, false);
    int p2 = __builtin_amdgcn_cvt_pk_fp8_f32(v1.x / scale, v1.y / scale, 0, false);
    int p3 = __builtin_amdgcn_cvt_pk_fp8_f32(v1.z / scale, v1.w / scale, 0, false);

    float r0 = __builtin_amdgcn_cvt_f32_fp8(p0, 0) * scale;
    float r1 = __builtin_amdgcn_cvt_f32_fp8(p0, 1) * scale;
    float r2 = __builtin_amdgcn_cvt_f32_fp8(p1, 0) * scale;
    float r3 = __builtin_amdgcn_cvt_f32_fp8(p1, 1) * scale;
    float r4 = __builtin_amdgcn_cvt_f32_fp8(p2, 0) * scale;
    float r5 = __builtin_amdgcn_cvt_f32_fp8(p2, 1) * scale;
    float r6 = __builtin_amdgcn_cvt_f32_fp8(p3, 0) * scale;
    float r7 = __builtin_amdgcn_cvt_f32_fp8(p3, 1) * scale;

    alignas(16) __hip_bfloat16 hb[8] = {
        __float2bfloat16(r0), __float2bfloat16(r1),
        __float2bfloat16(r2), __float2bfloat16(r3),
        __float2bfloat16(r4), __float2bfloat16(r5),
        __float2bfloat16(r6), __float2bfloat16(r7)};
    *(ushortx8*)(dst + base) = *(const ushortx8*)hb;
}

// ---------------------------------------------------------------------------
// bf16 NT GEMM + bias: 256x256 tile, BK=64, 512 thr (8 waves 2Mx4N),
// 8-phase counted-vmcnt schedule.
//   - ds_reads are PLAIN loads: compiler emits fine-grained lgkmcnt(N)
//     interleaved with MFMA issue (m97 asm evidence). NO explicit lgkm asm,
//     NO sched_barrier(0) -- that pinning was m141's -42% anti-pattern and
//     the cause of round-1's regression (MfmaUtil 39%).
//   - Only fences: raw s_barrier (no implicit vmcnt drain) + counted
//     s_waitcnt vmcnt(6) asm (memory clobber) at phases 4/8. vmcnt is the
//     only thing ordering global_load_lds completion vs ds_reads, and its
//     memory clobber also stops cross-buffer load hoisting.
//   - Staging schedule {ph1:A1(t+1); ph3:B0(t+2); ph4:B1,A0(t+2);
//     ph5:A1(t+2); ph7:B0(t+3); ph8:B1,A0(t+3)} is FORCED by the WAR map:
//     A-halves of a buffer are read in ph1+ph3, B-halves in ph1+ph2, so
//     buf slots only free at ph3(B0)/ph4(B1,A0)/ph5(A1) respectively.
//   - vmcnt(6) @ph4: 14 in flight, retires the 8 loads of tile t+1 (staged
//     prev ph7/ph8 + cur ph1) before ph5 reads buf1. @ph8 symmetric.
// Assumes M%256==0, N%256==0, K%128==0 (holds: 8192/4096/4096).
// ---------------------------------------------------------------------------

#define BAR() __builtin_amdgcn_s_barrier()
#define VMCNT(n) asm volatile("s_waitcnt vmcnt(" #n ")" ::: "memory")

#define STAGE_A(a_, t_, b_)                                                   \
  do {                                                                        \
    const __hip_bfloat16* g_ = gAs + (long)(a_) * 128 * K + (long)(t_) * 64;  \
    __hip_bfloat16* l_ = &sA[(b_)][(a_) * 8192 + tid * 8];                    \
    GLLDS16(g_, l_);                                                          \
    GLLDS16(g_ + 64 * (long)K, l_ + 4096);                                    \
  } while (0)

#define STAGE_B(a_, t_, b_)                                                   \
  do {                                                                        \
    const __hip_bfloat16* g_ = gBs + (long)(a_) * 128 * K + (long)(t_) * 64;  \
    __hip_bfloat16* l_ = &sB[(b_)][(a_) * 8192 + tid * 8];                    \
    GLLDS16(g_, l_);                                                          \
    GLLDS16(g_ + 64 * (long)K, l_ + 4096);                                    \
  } while (0)

#define LOAD_A(buf, mh)                                                       \
  do {                                                                        \
    _Pragma("unroll") for (int mm = 0; mm < 4; ++mm)                          \
    _Pragma("unroll") for (int ks = 0; ks < 2; ++ks)                          \
        af[mm][ks] = *(const bf16x8*)((buf) + ((mh)*4 + mm) * 1024 + aoff[ks]); \
  } while (0)

#define LOAD_B(buf, nh)                                                       \
  do {                                                                        \
    _Pragma("unroll") for (int nn = 0; nn < 2; ++nn)                          \
    _Pragma("unroll") for (int ks = 0; ks < 2; ++ks)                          \
        bfr[nh][nn][ks] = *(const bf16x8*)((buf) + (nh)*2048 + nn * 1024 + boff[ks]); \
  } while (0)

#define QUAD(mh, nh)                                                          \
  do {                                                                        \
    __builtin_amdgcn_s_setprio(1);                                            \
    _Pragma("unroll") for (int ks = 0; ks < 2; ++ks)                          \
    _Pragma("unroll") for (int mm = 0; mm < 4; ++mm)                          \
    _Pragma("unroll") for (int nn = 0; nn < 2; ++nn)                          \
        acc[(mh)*4 + mm][(nh)*2 + nn] = __builtin_amdgcn_mfma_f32_16x16x32_bf16( \
            af[mm][ks], bfr[nh][nn][ks], acc[(mh)*4 + mm][(nh)*2 + nn], 0, 0, 0); \
    __builtin_amdgcn_s_setprio(0);                                            \
  } while (0)

__global__ __launch_bounds__(512, 2) void gemm_bias_kernel(
    const __hip_bfloat16* __restrict__ A,   // [M][K]
    const __hip_bfloat16* __restrict__ B,   // [N][K]
    const float* __restrict__ bias,         // [N]
    float* __restrict__ C,                  // [M][N]
    int M, int N, int K)
{
    __shared__ __attribute__((aligned(16))) __hip_bfloat16 sA[2][256 * 64];
    __shared__ __attribute__((aligned(16))) __hip_bfloat16 sB[2][256 * 64];

    const int tid  = threadIdx.x;
    const int lane = tid & 63;
    const int wave = tid >> 6;
    const int wm   = wave >> 2;   // 0..1 : 128-row half
    const int wn   = wave & 3;    // 0..3 : 64-col slice

    // T1: XCD-aware bijective block swizzle (nwg % 8 == 0 for these shapes)
    const int nwg = gridDim.x;
    const int wg  = blockIdx.x;
    int swz = wg;
    if ((nwg & 7) == 0) swz = (wg & 7) * (nwg >> 3) + (wg >> 3);
    const int NXB = N >> 8;
    const long bm = (long)(swz / NXB) * 256;
    const long bn = (long)(swz % NXB) * 256;

    // staging: 512 thr * 16B = 64 rows (128B each) per GLLDS16 call
    const int srow   = tid >> 3;                   // 0..63
    const int schunk = (tid & 7) ^ (srow & 7);     // pre-swizzled global chunk
    const __hip_bfloat16* gAs = A + (bm + srow) * (long)K + schunk * 8;
    const __hip_bfloat16* gBs = B + (bn + srow) * (long)K + schunk * 8;

    const int fr = lane & 15;
    const int fq = lane >> 4;
    const int f7 = fr & 7;
    int aoff[2], boff[2];
#pragma unroll
    for (int ks = 0; ks < 2; ++ks) {
        const int ch = ((ks * 4 + fq) ^ f7) * 8;
        aoff[ks] = (wm * 128 + fr) * 64 + ch;
        boff[ks] = (wn * 64 + fr) * 64 + ch;
    }

    floatx4 acc[8][4];
#pragma unroll
    for (int i = 0; i < 8; ++i)
#pragma unroll
        for (int j = 0; j < 4; ++j)
            acc[i][j] = (floatx4){0.f, 0.f, 0.f, 0.f};

    bf16x8 af[4][2];        // current m-half A frags
    bf16x8 bfr[2][2][2];    // [nh][nn][ks] B frags, full K-tile

    const int NT = K >> 6;
    const int NI = NT >> 1;

    // prologue: tile0 fully -> buf0; tile1 B0,B1,A0 -> buf1 (A1 comes in ph1)
    STAGE_A(0, 0, 0); STAGE_A(1, 0, 0);
    STAGE_B(0, 0, 0); STAGE_B(1, 0, 0);
    if (NT > 1) { STAGE_B(0, 1, 1); STAGE_B(1, 1, 1); STAGE_A(0, 1, 1); }
    VMCNT(6);
    BAR();

#pragma unroll 1
    for (int i = 0; i < NI - 1; ++i) {
        const int t1 = 2 * i + 1, t2 = 2 * i + 2, t3 = 2 * i + 3;

        // ===== tile 2i from buf0 =====
        LOAD_A(sA[0], 0); LOAD_B(sB[0], 0);           // ph1: 12 reads
        STAGE_A(1, t1, 1);
        BAR();
        QUAD(0, 0);
        BAR();

        LOAD_B(sB[0], 1);                             // ph2: 4 reads
        BAR();
        QUAD(0, 1);
        BAR();

        LOAD_A(sA[0], 1);                             // ph3: 8 reads
        STAGE_B(0, t2, 0);
        BAR();
        QUAD(1, 0);
        BAR();

        STAGE_B(1, t2, 0); STAGE_A(0, t2, 0);         // ph4
        BAR();
        QUAD(1, 1);
        VMCNT(6);
        BAR();

        // ===== tile 2i+1 from buf1 =====
        LOAD_A(sA[1], 0); LOAD_B(sB[1], 0);           // ph5
        STAGE_A(1, t2, 0);
        BAR();
        QUAD(0, 0);
        BAR();

        LOAD_B(sB[1], 1);                             // ph6
        BAR();
        QUAD(0, 1);
        BAR();

        LOAD_A(sA[1], 1);                             // ph7
        STAGE_B(0, t3, 1);
        BAR();
        QUAD(1, 0);
        BAR();

        STAGE_B(1, t3, 1); STAGE_A(0, t3, 1);         // ph8
        BAR();
        QUAD(1, 1);
        VMCNT(6);
        BAR();
    }

    {   // ===== final iteration: no t+2/t+3 staging =====
        const int t1 = 2 * (NI - 1) + 1;

        LOAD_A(sA[0], 0); LOAD_B(sB[0], 0);
        STAGE_A(1, t1, 1);
        BAR();
        QUAD(0, 0);
        BAR();

        LOAD_B(sB[0], 1);
        BAR();
        QUAD(0, 1);
        BAR();

        LOAD_A(sA[0], 1);
        BAR();
        QUAD(1, 0);
        BAR();

        BAR();
        QUAD(1, 1);
        VMCNT(0);                                     // drain buf1's 8 loads
        BAR();

        LOAD_A(sA[1], 0); LOAD_B(sB[1], 0);
        BAR();
        QUAD(0, 0);
        BAR();

        LOAD_B(sB[1], 1);
        BAR();
        QUAD(0, 1);
        BAR();

        LOAD_A(sA[1], 1);
        BAR();
        QUAD(1, 0);
        BAR();

        QUAD(1, 1);
    }

    // epilogue: C/D layout col=lane&15, row=(lane>>4)*4+reg  [m89/m91]
    const int rq = (lane >> 4) * 4;
#pragma unroll
    for (int j = 0; j < 4; ++j) {
        const long gc = bn + wn * 64 + j * 16 + fr;
        const float bj = bias[gc];
#pragma unroll
        for (int mf = 0; mf < 8; ++mf) {
            const long gr = bm + wm * 128 + mf * 16 + rq;
            float* cp = C + gr * (long)N + gc;
#pragma unroll
            for (int r = 0; r < 4; ++r)
                cp[(long)r * N] = acc[mf][j][r] + bj;
        }
    }
}

extern "C" void kernel_launch(void* const* d_in, const int* in_sizes, int n_in,
                              void* d_out, int out_size, void* d_ws, size_t ws_size,
                              hipStream_t stream) {
    const float* x    = (const float*)d_in[0];   // [B,S,K] fp32
    const float* W    = (const float*)d_in[1];   // [N,K]   fp32
    const float* bias = (const float*)d_in[2];   // [N]     fp32
    float* out = (float*)d_out;

    const long long nx = in_sizes[0];
    const long long nw = in_sizes[1];
    const int N = in_sizes[2];
    const int K = (int)(nw / N);
    const int M = (int)(nx / K);

    __hip_bfloat16* xq = (__hip_bfloat16*)d_ws;
    __hip_bfloat16* wq = xq + nx;

    {
        long long tx = nx / 8;
        int blocks = (int)((tx + 255) / 256);
        quant_dq_kernel<<<blocks, 256, 0, stream>>>(x, xq, nx);
    }
    {
        long long tw = nw / 8;
        int blocks = (int)((tw + 255) / 256);
        quant_dq_kernel<<<blocks, 256, 0, stream>>>(W, wq, nw);
    }

    dim3 grid((N / 256) * (M / 256));
    gemm_bias_kernel<<<grid, 512, 0, stream>>>(xq, wq, bias, out, M, N, K);
}